// Round 2
// baseline (433.411 us; speedup 1.0000x reference)
//
#include <hip/hip_runtime.h>
#include <math.h>

#define Bn 512
#define Sn 1024
#define Tn 48

static constexpr float LOG2E = 1.4426950408889634f;
static constexpr float LN2f  = 0.6931471805599453f;

__device__ __forceinline__ float rlane(float x, int lane) {
  return __int_as_float(__builtin_amdgcn_readlane(__float_as_int(x), lane));
}
__device__ __forceinline__ float wave_max64(float v) {
  #pragma unroll
  for (int off = 32; off; off >>= 1) v = fmaxf(v, __shfl_xor(v, off));
  return v;
}

// One wave per batch, lane j owns state j (lanes 48..63 shadow state 47).
// Exp-domain forward scan: w_j = 2^(score_j - M). Per step:
//   w'_j = e_j * sum_i Ehat_ji * w_i,   Ehat = 2^(trans'-mtg) (constant, max 1),
//   e_j = 2^(em'_j)   (from prefetched emissions -> off the critical chain).
// Exact power-of-2 renorm every 4 steps; M recovers mtg via mask count at end.
// Ehat row kept in 48 NAMED registers (round-1 array was demoted to scratch:
// VGPR_Count=36 + 737cy/step => ~48 private buffer_loads per step).

#define DECL_E1(i) const float E_##i = __builtin_amdgcn_exp2f(fmaf(trow[i], LOG2E, -mtg));
#define DECL_E_ALL \
  DECL_E1(0) DECL_E1(1) DECL_E1(2) DECL_E1(3) DECL_E1(4) DECL_E1(5) \
  DECL_E1(6) DECL_E1(7) DECL_E1(8) DECL_E1(9) DECL_E1(10) DECL_E1(11) \
  DECL_E1(12) DECL_E1(13) DECL_E1(14) DECL_E1(15) DECL_E1(16) DECL_E1(17) \
  DECL_E1(18) DECL_E1(19) DECL_E1(20) DECL_E1(21) DECL_E1(22) DECL_E1(23) \
  DECL_E1(24) DECL_E1(25) DECL_E1(26) DECL_E1(27) DECL_E1(28) DECL_E1(29) \
  DECL_E1(30) DECL_E1(31) DECL_E1(32) DECL_E1(33) DECL_E1(34) DECL_E1(35) \
  DECL_E1(36) DECL_E1(37) DECL_E1(38) DECL_E1(39) DECL_E1(40) DECL_E1(41) \
  DECL_E1(42) DECL_E1(43) DECL_E1(44) DECL_E1(45) DECL_E1(46) DECL_E1(47)

#define ACC1(i,k) a##k = fmaf(rlane(w, i), E_##i, a##k);
#define ACC4(i0,i1,i2,i3) ACC1(i0,0) ACC1(i1,1) ACC1(i2,2) ACC1(i3,3)
#define ACC_ALL \
  ACC4(0,1,2,3)     ACC4(4,5,6,7)     ACC4(8,9,10,11)   ACC4(12,13,14,15) \
  ACC4(16,17,18,19) ACC4(20,21,22,23) ACC4(24,25,26,27) ACC4(28,29,30,31) \
  ACC4(32,33,34,35) ACC4(36,37,38,39) ACC4(40,41,42,43) ACC4(44,45,46,47)

__global__ __launch_bounds__(64) void crf_fwd(
    const float* __restrict__ emissions,
    const int*   __restrict__ tags,
    const float* __restrict__ mask,
    const float* __restrict__ trans,
    const float* __restrict__ startt,
    const float* __restrict__ endt,
    float* __restrict__ per_batch)
{
  const int b  = blockIdx.x;
  const int j  = threadIdx.x;
  const int jc = (j < Tn) ? j : (Tn - 1);

  const float* __restrict__ emb = emissions + (size_t)b * Sn * Tn;
  const int*   __restrict__ tgb = tags + (size_t)b * Sn;
  const float* __restrict__ mkb = mask + (size_t)b * Sn;
  const float* __restrict__ trow = trans + jc * Tn;

  // Global max of transitions (log2 domain) for Ehat normalization.
  float mt = trow[0];
  #pragma unroll
  for (int i = 1; i < Tn; ++i) mt = fmaxf(mt, trow[i]);
  const float mtg = wave_max64(mt) * LOG2E;   // lanes 48..63 duplicate row 47: harmless for max

  DECL_E_ALL   // 48 named registers: Ehat row jc, in (0,1], log2-normalized

  // Init (step 0).
  const float em0  = emb[jc];
  const int   tag0 = tgb[0];
  const float sc0  = (startt[jc] + em0) * LOG2E;
  const float m00  = wave_max64(sc0);
  float w = __builtin_amdgcn_exp2f(sc0 - m00);
  float M = m00;                       // accumulated log2 shift (mtg*cnt added at end)
  float numer = rlane(em0, tag0) + startt[tag0];   // lane-uniform, natural domain
  float cnt = 0.0f;                    // sum of mask over steps 1..S-1
  int   lt  = tag0;

  auto do_step = [&](float em_raw, float e, float mk, int tg, float tval) {
    float a0 = 0.f, a1 = 0.f, a2 = 0.f, a3 = 0.f;
    ACC_ALL
    const float nxt = ((a0 + a1) + (a2 + a3)) * e;
    const bool on = (mk > 0.0f);
    w  = on ? nxt : w;
    numer = fmaf(mk, rlane(em_raw, tg) + tval, numer);
    cnt += mk;
    lt  = on ? tg : lt;
  };

  auto renorm = [&]() {
    const float m = wave_max64(w);                      // m in (0, 2^57]
    const int  mb = __float_as_int(m) & 0x7f800000;     // 2^E bits (m normal, positive)
    w *= __int_as_float(0x7f000000 - mb);               // exact * 2^-E
    M += (float)((mb >> 23) - 127);                     // exact integer add
  };

  // Prologue: steps 1..3, unpipelined.
  #pragma unroll
  for (int s = 1; s < 4; ++s) {
    const float er = emb[s*Tn + jc];
    const float mk = mkb[s];
    const int   tg = tgb[s];
    const int   tp = tgb[s-1];
    const float tv = trans[tg*Tn + tp];
    const float e  = __builtin_amdgcn_exp2f(er * LOG2E);
    do_step(er, e, mk, tg, tv);
  }
  renorm();

  // Preload chunk s0 = 4.
  float ec0 = emb[4*Tn + jc], ec1 = emb[5*Tn + jc],
        ec2 = emb[6*Tn + jc], ec3 = emb[7*Tn + jc];
  int4   tgc = *(const int4*)(tgb + 4);
  float4 mkc = *(const float4*)(mkb + 4);
  float tv0, tv1, tv2, tv3;
  {
    const int ptail = tgb[3];
    tv0 = trans[tgc.x*Tn + ptail];
    tv1 = trans[tgc.y*Tn + tgc.x];
    tv2 = trans[tgc.z*Tn + tgc.y];
    tv3 = trans[tgc.w*Tn + tgc.z];
  }

  // Pipelined main loop: process chunk s0, prefetch chunk s0+4, renorm per chunk.
  for (int s0 = 4; s0 + 4 < Sn; s0 += 4) {
    const int sn = s0 + 4;
    const float en0 = emb[(sn+0)*Tn + jc];
    const float en1 = emb[(sn+1)*Tn + jc];
    const float en2 = emb[(sn+2)*Tn + jc];
    const float en3 = emb[(sn+3)*Tn + jc];
    const int4   tgn = *(const int4*)(tgb + sn);
    const float4 mkn = *(const float4*)(mkb + sn);

    // e's for the current chunk: inputs already resident -> off the chain.
    const float e0 = __builtin_amdgcn_exp2f(ec0 * LOG2E);
    const float e1 = __builtin_amdgcn_exp2f(ec1 * LOG2E);
    const float e2 = __builtin_amdgcn_exp2f(ec2 * LOG2E);
    const float e3 = __builtin_amdgcn_exp2f(ec3 * LOG2E);

    do_step(ec0, e0, mkc.x, tgc.x, tv0);
    do_step(ec1, e1, mkc.y, tgc.y, tv1);
    do_step(ec2, e2, mkc.z, tgc.z, tv2);
    do_step(ec3, e3, mkc.w, tgc.w, tv3);
    renorm();

    tv0 = trans[tgn.x*Tn + tgc.w];
    tv1 = trans[tgn.y*Tn + tgn.x];
    tv2 = trans[tgn.z*Tn + tgn.y];
    tv3 = trans[tgn.w*Tn + tgn.z];
    ec0 = en0; ec1 = en1; ec2 = en2; ec3 = en3;
    tgc = tgn; mkc = mkn;
  }
  // Tail chunk (steps 1020..1023).
  {
    const float e0 = __builtin_amdgcn_exp2f(ec0 * LOG2E);
    const float e1 = __builtin_amdgcn_exp2f(ec1 * LOG2E);
    const float e2 = __builtin_amdgcn_exp2f(ec2 * LOG2E);
    const float e3 = __builtin_amdgcn_exp2f(ec3 * LOG2E);
    do_step(ec0, e0, mkc.x, tgc.x, tv0);
    do_step(ec1, e1, mkc.y, tgc.y, tv1);
    do_step(ec2, e2, mkc.z, tgc.z, tv2);
    do_step(ec3, e3, mkc.w, tgc.w, tv3);
  }

  // Denominator: den = (M + mtg*cnt + log2(sum_j w_j * 2^(end'_j))) * ln2.
  float z = (j < Tn) ? w * __builtin_amdgcn_exp2f(endt[jc] * LOG2E) : 0.0f;
  #pragma unroll
  for (int off = 32; off; off >>= 1) z += __shfl_xor(z, off);
  const float den = (M + fmaf(mtg, cnt, __builtin_amdgcn_logf(z))) * LN2f;

  const float nm = numer + endt[lt];   // lane-uniform
  if (j == 0) per_batch[b] = den - nm;
}

__global__ __launch_bounds__(512) void reduce512(const float* __restrict__ pb,
                                                 float* __restrict__ out) {
  __shared__ float red[8];
  const int t = threadIdx.x;
  float v = pb[t];
  #pragma unroll
  for (int off = 32; off; off >>= 1) v += __shfl_xor(v, off);
  if ((t & 63) == 0) red[t >> 6] = v;
  __syncthreads();
  if (t == 0) {
    float s = 0.f;
    #pragma unroll
    for (int wv = 0; wv < 8; ++wv) s += red[wv];
    out[0] = s * (1.0f / 512.0f);
  }
}

extern "C" void kernel_launch(void* const* d_in, const int* in_sizes, int n_in,
                              void* d_out, int out_size, void* d_ws, size_t ws_size,
                              hipStream_t stream) {
  const float* emissions = (const float*)d_in[0];
  const int*   tags      = (const int*)d_in[1];
  const float* mask      = (const float*)d_in[2];
  const float* trans     = (const float*)d_in[3];
  const float* startt    = (const float*)d_in[4];
  const float* endt      = (const float*)d_in[5];
  float* pb = (float*)d_ws;   // 512 floats of scratch

  crf_fwd<<<Bn, 64, 0, stream>>>(emissions, tags, mask, trans, startt, endt, pb);
  reduce512<<<1, 512, 0, stream>>>(pb, (float*)d_out);
}